// Round 1
// baseline (311.656 us; speedup 1.0000x reference)
//
#include <hip/hip_runtime.h>

// Problem constants (B, Cin, Cout, H, W) = (8, 256, 256, 128, 128)
#define BATCH 8
#define CIN   256
#define COUT  256
#define HH    128
#define WW    128
#define HW    (HH*WW)          // 16384

typedef __bf16 bf16x8 __attribute__((ext_vector_type(8)));
typedef float  f32x4  __attribute__((ext_vector_type(4)));

__device__ __forceinline__ unsigned short f2bf(float f) {
    unsigned u = __float_as_uint(f);
    unsigned r = (u + 0x7fffu + ((u >> 16) & 1u)) >> 16;   // round-to-nearest-even
    return (unsigned short)r;
}

// ---------------------------------------------------------------------------
// Kernel 1 (fused): depthwise 3x3 conv (pad=1) -> bf16 transposed Tt[b][p][c],
// 4 h-rows per block (x re-read 3x -> 1.5x, halo rows L1/L2-hot), plus the
// W_b prep folded in as 64 trailing blocks.
// XCD swizzle: conv blocks remapped so XCD i owns batch i (contiguous logical
// range) -> x row overlap served by same-XCD L2, and Tt[b] is written by the
// same XCD that reads it in the GEMM.
// ---------------------------------------------------------------------------
#define CONV_BLOCKS 1024   // 32 hb * 4 cb * 8 b
#define PREP_BLOCKS 64

__global__ __launch_bounds__(256) void dwconv_prep_kernel(
    const float* __restrict__ x, const float* __restrict__ dw,
    const float* __restrict__ delta, const float* __restrict__ pw,
    unsigned short* __restrict__ Tt, unsigned short* __restrict__ Wb)
{
    const int tid = threadIdx.x;

    if ((int)blockIdx.x >= CONV_BLOCKS) {
        // ---- prep path: W_b[b][o][c] = bf16(pw[o][c] + delta[b][o][c]) ----
        // 64 blocks * 256 threads * 8 quads = 131072 quads = 8*256*256/4.
        const int t0 = (((int)blockIdx.x - CONV_BLOCKS) * 256 + tid) * 8;
        #pragma unroll
        for (int qq = 0; qq < 8; ++qq) {
            const int i = t0 + qq;                       // quad index
            float4 d = *(const float4*)(delta + (size_t)i * 4);
            const int j = (i * 4) & (COUT * CIN - 1);    // pw index (o*256+c)
            float4 p = *(const float4*)(pw + j);
            ushort4 r;
            r.x = f2bf(d.x + p.x);
            r.y = f2bf(d.y + p.y);
            r.z = f2bf(d.z + p.z);
            r.w = f2bf(d.w + p.w);
            *(ushort4*)(Wb + (size_t)i * 4) = r;
        }
        return;
    }

    __shared__ unsigned short tile[128 * 66];   // [w][c] row stride 66 ushorts
    __shared__ float kw[64 * 9];

    // bijective XCD swizzle: XCD (bid&7) gets contiguous logical range of 128
    // blocks = one full batch (32 hb * 4 cb).
    const int L  = ((int)blockIdx.x & 7) * (CONV_BLOCKS / 8) + ((int)blockIdx.x >> 3);
    const int hb = L & 31;          // 4 h-rows: hb*4 .. hb*4+3
    const int cb = (L >> 5) & 3;    // 64-channel group
    const int b  = L >> 7;          // batch == XCD index

    // stage this block's 64 channels' 3x3 weights: 576 floats = 144 float4
    if (tid < 144) {
        float4 v = *(const float4*)(dw + (size_t)cb * 576 + (size_t)tid * 4);
        *(float4*)(kw + tid * 4) = v;
    }
    __syncthreads();

    const int wq = tid & 31;     // w-quad: covers w0..w0+3
    const int cs = tid >> 5;     // 0..7 channel subgroup
    const int w0 = wq * 4;

    for (int hh = 0; hh < 4; ++hh) {
        const int h = hb * 4 + hh;

        // Phase A: conv -> LDS tile [w=128][c=64]
        for (int ci = 0; ci < 8; ++ci) {
            const int c = ci * 8 + cs;                       // local channel 0..63
            const float* xp = x + ((size_t)(b * CIN + cb * 64 + c)) * HW;
            const float* kc = kw + c * 9;
            float a0 = 0.f, a1 = 0.f, a2 = 0.f, a3 = 0.f;
            #pragma unroll
            for (int dy = 0; dy < 3; ++dy) {
                const int r = h + dy - 1;
                float4 v = {0.f, 0.f, 0.f, 0.f};
                if (r >= 0 && r < HH) v = *(const float4*)(xp + r * WW + w0);
                float lft = __shfl_up(v.w, 1);    // lane-1's last element
                float rgt = __shfl_down(v.x, 1);  // lane+1's first element
                if (wq == 0)  lft = 0.f;          // w=-1 pad
                if (wq == 31) rgt = 0.f;          // w=128 pad
                const float k0 = kc[dy * 3 + 0], k1 = kc[dy * 3 + 1], k2 = kc[dy * 3 + 2];
                a0 += k0 * lft + k1 * v.x + k2 * v.y;
                a1 += k0 * v.x + k1 * v.y + k2 * v.z;
                a2 += k0 * v.y + k1 * v.z + k2 * v.w;
                a3 += k0 * v.z + k1 * v.w + k2 * rgt;
            }
            const int base = w0 * 66 + c;
            tile[base]       = f2bf(a0);
            tile[base + 66]  = f2bf(a1);
            tile[base + 132] = f2bf(a2);
            tile[base + 198] = f2bf(a3);
        }
        __syncthreads();

        // Phase B: transposed write-out. lane pair covers 2 consecutive c.
        {
            const int cpair = tid & 31;   // c = 2*cpair .. 2*cpair+1
            const int wg    = tid >> 5;   // 8 w-groups of 16
            const size_t prow = (size_t)b * HW + (size_t)h * WW;
            #pragma unroll
            for (int wi = 0; wi < 16; ++wi) {
                const int w = wg * 16 + wi;
                unsigned v = *(const unsigned*)&tile[w * 66 + cpair * 2];
                *(unsigned*)&Tt[(prow + w) * CIN + cb * 64 + cpair * 2] = v;
            }
        }
        __syncthreads();   // tile reused next hh
    }
}

// ---------------------------------------------------------------------------
// Kernel 2: per-batch GEMM  out[b][o][p] = sum_c Wb[b][o][c] * Tt[b][p][c]
// Changes vs prev round:
//  - BK=64 (4 K-steps instead of 8 -> half the barrier/vmcnt(0) drains)
//  - XOR-swizzled LDS (slot ^= row&7, 16B granule): conflict-free ds_read_b128
//    (would be 16-way at 128B row stride). global_load_lds writes linearly, so
//    the swizzle is applied to the GLOBAL source address + the LDS read address
//    (rule #21: both-sides-or-neither).
//  - XCD swizzle: batch b == XCD b (matches dwconv's Tt writer), mt-pairs
//    adjacent -> B tile read twice from L2; A panel (128 KiB) L2-resident.
// ---------------------------------------------------------------------------
__global__ __launch_bounds__(256) void gemm_kernel(
    const unsigned short* __restrict__ Wb,
    const unsigned short* __restrict__ Tt,
    float* __restrict__ out)
{
    __shared__ unsigned short lA[128 * 64];   // [row][slot^ (row&7)], 16B slots
    __shared__ unsigned short lB[128 * 64];

    // 2048 blocks: XCD (bid&7) owns logical range 256 = one batch; within it
    // mt toggles fastest, then nt.
    const int L  = ((int)blockIdx.x & 7) * 256 + ((int)blockIdx.x >> 3);
    const int mt = L & 1;
    const int nt = (L >> 1) & 127;
    const int b  = L >> 8;
    const int tid = threadIdx.x;

    const unsigned short* Ab = Wb + ((size_t)b * COUT + mt * 128) * CIN;   // [128][256]
    const unsigned short* Bb = Tt + ((size_t)b * HW + nt * 128) * CIN;     // [128][256]

    const int lane = tid & 63;
    const int wv   = tid >> 6;
    const int wm   = (wv & 1) * 64;
    const int wn   = (wv >> 1) * 64;
    const int q    = lane >> 4;     // quad 0..3
    const int rrow = lane & 15;

    f32x4 acc[4][4] = {};

    for (int k0 = 0; k0 < CIN; k0 += 64) {
        #pragma unroll
        for (int r = 0; r < 4; ++r) {
            const int i     = r * 256 + tid;    // 16B chunk id, 0..1023
            const int row   = i >> 3;           // 0..127
            const int pslot = i & 7;            // physical 16B slot in row
            const int lslot = pslot ^ (row & 7);// logical slot fetched here
            const unsigned short* ga = Ab + (size_t)row * CIN + k0 + lslot * 8;
            const unsigned short* gb = Bb + (size_t)row * CIN + k0 + lslot * 8;
            __builtin_amdgcn_global_load_lds(
                (const __attribute__((address_space(1))) void*)ga,
                (__attribute__((address_space(3))) void*)(lA + (size_t)i * 8),
                16, 0, 0);
            __builtin_amdgcn_global_load_lds(
                (const __attribute__((address_space(1))) void*)gb,
                (__attribute__((address_space(3))) void*)(lB + (size_t)i * 8),
                16, 0, 0);
        }
        __syncthreads();

        #pragma unroll
        for (int kk = 0; kk < 2; ++kk) {
            bf16x8 af[4], bfv[4];
            const int slot = (kk * 4 + q) ^ (rrow & 7);   // row&7 == rrow&7 here
            #pragma unroll
            for (int i = 0; i < 4; ++i) {
                af[i]  = *(const bf16x8*)&lA[(wm + i * 16 + rrow) * 64 + slot * 8];
                bfv[i] = *(const bf16x8*)&lB[(wn + i * 16 + rrow) * 64 + slot * 8];
            }
            #pragma unroll
            for (int i = 0; i < 4; ++i)
                #pragma unroll
                for (int j = 0; j < 4; ++j)
                    acc[i][j] = __builtin_amdgcn_mfma_f32_16x16x32_bf16(af[i], bfv[j], acc[i][j], 0, 0, 0);
        }
        __syncthreads();
    }

    // epilogue: C/D map col=lane&15, row=quad*4+reg
    float* outp = out + ((size_t)b * COUT + mt * 128 + wm) * HW + (size_t)nt * 128 + wn;
    #pragma unroll
    for (int i = 0; i < 4; ++i)
        #pragma unroll
        for (int j = 0; j < 4; ++j)
            #pragma unroll
            for (int rr = 0; rr < 4; ++rr)
                outp[(size_t)(i * 16 + q * 4 + rr) * HW + j * 16 + rrow] = acc[i][j][rr];
}

// ---------------------------------------------------------------------------
extern "C" void kernel_launch(void* const* d_in, const int* in_sizes, int n_in,
                              void* d_out, int out_size, void* d_ws, size_t ws_size,
                              hipStream_t stream)
{
    const float* x     = (const float*)d_in[0];   // (8,256,128,128)
    const float* delta = (const float*)d_in[1];   // (8,256,256,1,1)
    const float* dw    = (const float*)d_in[2];   // (256,1,3,3)
    const float* pw    = (const float*)d_in[3];   // (256,256,1,1)
    float* out = (float*)d_out;                   // (8,256,128,128)

    // workspace: Tt bf16 [8][16384][256] = 64 MiB, then Wb bf16 [8][256][256] = 1 MiB
    unsigned short* Tt = (unsigned short*)d_ws;
    unsigned short* Wb = (unsigned short*)((char*)d_ws + (size_t)BATCH * HW * CIN * 2);

    dwconv_prep_kernel<<<dim3(CONV_BLOCKS + PREP_BLOCKS), dim3(256), 0, stream>>>(
        x, dw, delta, pw, Tt, Wb);
    gemm_kernel<<<dim3(2048), dim3(256), 0, stream>>>(Wb, Tt, out);
}

// Round 3
// 301.027 us; speedup vs baseline: 1.0353x; 1.0353x over previous
//
#include <hip/hip_runtime.h>

// Problem constants (B, Cin, Cout, H, W) = (8, 256, 256, 128, 128)
#define BATCH 8
#define CIN   256
#define COUT  256
#define HH    128
#define WW    128
#define HW    (HH*WW)          // 16384

typedef __bf16 bf16x8 __attribute__((ext_vector_type(8)));
typedef float  f32x4  __attribute__((ext_vector_type(4)));

__device__ __forceinline__ unsigned short f2bf(float f) {
    unsigned u = __float_as_uint(f);
    unsigned r = (u + 0x7fffu + ((u >> 16) & 1u)) >> 16;   // round-to-nearest-even
    return (unsigned short)r;
}

// ---------------------------------------------------------------------------
// Kernel 1 (fused): depthwise 3x3 conv (pad=1) -> bf16 transposed Tt[b][p][c].
// R1 post-mortem: 4-row blocks (1024) were latency-bound (occ 39%, 35% BW).
// R2: 2-row blocks -> 2048 blocks = 8 blocks/CU (LDS limit), raw redundancy
// 2x (320 MB total), XCD swizzle with hb FASTEST within an XCD so adjacent-hb
// blocks (sharing 2 halo rows) run back-to-back for L2 reuse.
// Prep (W_b = pw + delta) folded in as 64 trailing blocks.
// ---------------------------------------------------------------------------
#define CONV_BLOCKS 2048   // 64 hb * 4 cb * 8 b
#define PREP_BLOCKS 64

__global__ __launch_bounds__(256) void dwconv_prep_kernel(
    const float* __restrict__ x, const float* __restrict__ dw,
    const float* __restrict__ delta, const float* __restrict__ pw,
    unsigned short* __restrict__ Tt, unsigned short* __restrict__ Wb)
{
    const int tid = threadIdx.x;

    if ((int)blockIdx.x >= CONV_BLOCKS) {
        // ---- prep path: W_b[b][o][c] = bf16(pw[o][c] + delta[b][o][c]) ----
        // 64 blocks * 256 threads * 8 quads = 131072 quads = 8*256*256/4.
        const int t0 = (((int)blockIdx.x - CONV_BLOCKS) * 256 + tid) * 8;
        #pragma unroll
        for (int qq = 0; qq < 8; ++qq) {
            const int i = t0 + qq;                       // quad index
            float4 d = *(const float4*)(delta + (size_t)i * 4);
            const int j = (i * 4) & (COUT * CIN - 1);    // pw index (o*256+c)
            float4 p = *(const float4*)(pw + j);
            ushort4 r;
            r.x = f2bf(d.x + p.x);
            r.y = f2bf(d.y + p.y);
            r.z = f2bf(d.z + p.z);
            r.w = f2bf(d.w + p.w);
            *(ushort4*)(Wb + (size_t)i * 4) = r;
        }
        return;
    }

    __shared__ unsigned short tile[128 * 66];   // [w][c] row stride 66 ushorts
    __shared__ float kw[64 * 9];

    // bijective XCD swizzle: XCD (bid&7) owns batch (bid&7); within the XCD,
    // hb varies fastest (adjacent hb share 2 halo rows -> L2 hits), then cb.
    const int L  = ((int)blockIdx.x & 7) * (CONV_BLOCKS / 8) + ((int)blockIdx.x >> 3);
    const int hb = L & 63;          // 2 h-rows: hb*2, hb*2+1
    const int cb = (L >> 6) & 3;    // 64-channel group
    const int b  = L >> 8;          // batch == XCD index

    // stage this block's 64 channels' 3x3 weights: 576 floats = 144 float4
    if (tid < 144) {
        float4 v = *(const float4*)(dw + (size_t)cb * 576 + (size_t)tid * 4);
        *(float4*)(kw + tid * 4) = v;
    }
    __syncthreads();

    const int wq = tid & 31;     // w-quad: covers w0..w0+3
    const int cs = tid >> 5;     // 0..7 channel subgroup
    const int w0 = wq * 4;

    for (int hh = 0; hh < 2; ++hh) {
        const int h = hb * 2 + hh;

        // Phase A: conv -> LDS tile [w=128][c=64]
        for (int ci = 0; ci < 8; ++ci) {
            const int c = ci * 8 + cs;                       // local channel 0..63
            const float* xp = x + ((size_t)(b * CIN + cb * 64 + c)) * HW;
            const float* kc = kw + c * 9;
            float a0 = 0.f, a1 = 0.f, a2 = 0.f, a3 = 0.f;
            #pragma unroll
            for (int dy = 0; dy < 3; ++dy) {
                const int r = h + dy - 1;
                float4 v = {0.f, 0.f, 0.f, 0.f};
                if (r >= 0 && r < HH) v = *(const float4*)(xp + r * WW + w0);
                float lft = __shfl_up(v.w, 1);    // lane-1's last element
                float rgt = __shfl_down(v.x, 1);  // lane+1's first element
                if (wq == 0)  lft = 0.f;          // w=-1 pad
                if (wq == 31) rgt = 0.f;          // w=128 pad
                const float k0 = kc[dy * 3 + 0], k1 = kc[dy * 3 + 1], k2 = kc[dy * 3 + 2];
                a0 += k0 * lft + k1 * v.x + k2 * v.y;
                a1 += k0 * v.x + k1 * v.y + k2 * v.z;
                a2 += k0 * v.y + k1 * v.z + k2 * v.w;
                a3 += k0 * v.z + k1 * v.w + k2 * rgt;
            }
            const int base = w0 * 66 + c;
            tile[base]       = f2bf(a0);
            tile[base + 66]  = f2bf(a1);
            tile[base + 132] = f2bf(a2);
            tile[base + 198] = f2bf(a3);
        }
        __syncthreads();

        // Phase B: transposed write-out. lane pair covers 2 consecutive c.
        {
            const int cpair = tid & 31;   // c = 2*cpair .. 2*cpair+1
            const int wg    = tid >> 5;   // 8 w-groups of 16
            const size_t prow = (size_t)b * HW + (size_t)h * WW;
            #pragma unroll
            for (int wi = 0; wi < 16; ++wi) {
                const int w = wg * 16 + wi;
                unsigned v = *(const unsigned*)&tile[w * 66 + cpair * 2];
                *(unsigned*)&Tt[(prow + w) * CIN + cb * 64 + cpair * 2] = v;
            }
        }
        __syncthreads();   // tile reused next hh
    }
}

// ---------------------------------------------------------------------------
// Kernel 2: per-batch GEMM  out[b][o][p] = sum_c Wb[b][o][c] * Tt[b][p][c]
// UNCHANGED from R1 (BK=64, XOR-swizzled LDS via pre-swizzled global source,
// XCD swizzle batch==XCD) — held fixed to isolate the conv delta.
// ---------------------------------------------------------------------------
__global__ __launch_bounds__(256) void gemm_kernel(
    const unsigned short* __restrict__ Wb,
    const unsigned short* __restrict__ Tt,
    float* __restrict__ out)
{
    __shared__ unsigned short lA[128 * 64];   // [row][slot ^ (row&7)], 16B slots
    __shared__ unsigned short lB[128 * 64];

    // 2048 blocks: XCD (bid&7) owns logical range 256 = one batch; within it
    // mt toggles fastest, then nt.
    const int L  = ((int)blockIdx.x & 7) * 256 + ((int)blockIdx.x >> 3);
    const int mt = L & 1;
    const int nt = (L >> 1) & 127;
    const int b  = L >> 8;
    const int tid = threadIdx.x;

    const unsigned short* Ab = Wb + ((size_t)b * COUT + mt * 128) * CIN;   // [128][256]
    const unsigned short* Bb = Tt + ((size_t)b * HW + nt * 128) * CIN;     // [128][256]

    const int lane = tid & 63;
    const int wv   = tid >> 6;
    const int wm   = (wv & 1) * 64;
    const int wn   = (wv >> 1) * 64;
    const int q    = lane >> 4;     // quad 0..3
    const int rrow = lane & 15;

    f32x4 acc[4][4] = {};

    for (int k0 = 0; k0 < CIN; k0 += 64) {
        #pragma unroll
        for (int r = 0; r < 4; ++r) {
            const int i     = r * 256 + tid;    // 16B chunk id, 0..1023
            const int row   = i >> 3;           // 0..127
            const int pslot = i & 7;            // physical 16B slot in row
            const int lslot = pslot ^ (row & 7);// logical slot fetched here
            const unsigned short* ga = Ab + (size_t)row * CIN + k0 + lslot * 8;
            const unsigned short* gb = Bb + (size_t)row * CIN + k0 + lslot * 8;
            __builtin_amdgcn_global_load_lds(
                (const __attribute__((address_space(1))) void*)ga,
                (__attribute__((address_space(3))) void*)(lA + (size_t)i * 8),
                16, 0, 0);
            __builtin_amdgcn_global_load_lds(
                (const __attribute__((address_space(1))) void*)gb,
                (__attribute__((address_space(3))) void*)(lB + (size_t)i * 8),
                16, 0, 0);
        }
        __syncthreads();

        #pragma unroll
        for (int kk = 0; kk < 2; ++kk) {
            bf16x8 af[4], bfv[4];
            const int slot = (kk * 4 + q) ^ (rrow & 7);   // row&7 == rrow&7 here
            #pragma unroll
            for (int i = 0; i < 4; ++i) {
                af[i]  = *(const bf16x8*)&lA[(wm + i * 16 + rrow) * 64 + slot * 8];
                bfv[i] = *(const bf16x8*)&lB[(wn + i * 16 + rrow) * 64 + slot * 8];
            }
            #pragma unroll
            for (int i = 0; i < 4; ++i)
                #pragma unroll
                for (int j = 0; j < 4; ++j)
                    acc[i][j] = __builtin_amdgcn_mfma_f32_16x16x32_bf16(af[i], bfv[j], acc[i][j], 0, 0, 0);
        }
        __syncthreads();
    }

    // epilogue: C/D map col=lane&15, row=quad*4+reg
    float* outp = out + ((size_t)b * COUT + mt * 128 + wm) * HW + (size_t)nt * 128 + wn;
    #pragma unroll
    for (int i = 0; i < 4; ++i)
        #pragma unroll
        for (int j = 0; j < 4; ++j)
            #pragma unroll
            for (int rr = 0; rr < 4; ++rr)
                outp[(size_t)(i * 16 + q * 4 + rr) * HW + j * 16 + rrow] = acc[i][j][rr];
}

// ---------------------------------------------------------------------------
extern "C" void kernel_launch(void* const* d_in, const int* in_sizes, int n_in,
                              void* d_out, int out_size, void* d_ws, size_t ws_size,
                              hipStream_t stream)
{
    const float* x     = (const float*)d_in[0];   // (8,256,128,128)
    const float* delta = (const float*)d_in[1];   // (8,256,256,1,1)
    const float* dw    = (const float*)d_in[2];   // (256,1,3,3)
    const float* pw    = (const float*)d_in[3];   // (256,256,1,1)
    float* out = (float*)d_out;                   // (8,256,128,128)

    // workspace: Tt bf16 [8][16384][256] = 64 MiB, then Wb bf16 [8][256][256] = 1 MiB
    unsigned short* Tt = (unsigned short*)d_ws;
    unsigned short* Wb = (unsigned short*)((char*)d_ws + (size_t)BATCH * HW * CIN * 2);

    dwconv_prep_kernel<<<dim3(CONV_BLOCKS + PREP_BLOCKS), dim3(256), 0, stream>>>(
        x, dw, delta, pw, Tt, Wb);
    gemm_kernel<<<dim3(2048), dim3(256), 0, stream>>>(Wb, Tt, out);
}